// Round 5
// baseline (159.237 us; speedup 1.0000x reference)
//
#include <hip/hip_runtime.h>

#define GX 432
#define GY 496
#define G_TOTAL (GX * GY) /* 214272, GZ=1 */
#define MAX_PTS 32
#define MAX_VOX 20000
#define CAP 64
#define INF_SENTINEL 0x7F7F7F7F
#define PREFIX_K 262144 /* ~133k in-range claims -> ~99k distinct cells >> 20000 */

typedef unsigned long long u64;

// IEEE float32 ops exactly matching the reference:
// c = floor((p - lo)/vs), lo = [0, -39.68, -3], vs = [.16,.16,4].
__device__ __forceinline__ int cell_of(float4 p, bool& ok) {
    float fx = floorf((p.x - 0.0f) / 0.16f);
    float fy = floorf((p.y + 39.68f) / 0.16f);
    float fz = floorf((p.z + 3.0f) / 4.0f);
    int cx = (int)fx, cy = (int)fy, cz = (int)fz;
    ok = (cx >= 0 && cx < GX && cy >= 0 && cy < GY && cz == 0);
    return cy * GX + cx;
}

// K1: fused initialization of every table consumed downstream.
// rank[] MUST be inited to INF: under the prefix heuristic, cells whose
// first point is >= K are never ranked, but kAppend reads rank[c] for any
// in-range cell (round-4 crash: poisoned rank read -> negative vr -> OOB
// atomic). INF filters them.
__global__ __launch_bounds__(256) void kInit(int* __restrict__ first,
                                             int* __restrict__ rank,
                                             u64* __restrict__ bits,
                                             int* __restrict__ vcount,
                                             int* __restrict__ cellOfRank,
                                             int* __restrict__ dcount, int W) {
    int i = blockIdx.x * 256 + threadIdx.x;
    if (i < G_TOTAL) { first[i] = INF_SENTINEL; rank[i] = INF_SENTINEL; }
    if (i < W) bits[i] = 0ull;
    if (i < MAX_VOX) { vcount[i] = -1; cellOfRank[i] = -1; }
    if (i == 0) *dcount = 0;
}

// K2: point pass — lin[] store for ALL points; atomicMin claim ONLY for the
// prefix i < K (round-3 lesson: device-scope atomics are memory-side on
// multi-XCD and cap at ~23 Gop/s -> 1M atomics = 32 us; 133K = ~4 us).
// Distinct-cell count is fused in via the atomicMin return value: old==INF
// exactly once per cell; wave-ballot reduce, one atomicAdd per wave.
__global__ __launch_bounds__(256) void kPoints(const float4* __restrict__ pts,
                                               int* __restrict__ lin,
                                               int* __restrict__ first,
                                               int* __restrict__ dcount,
                                               int K, int n) {
    int i = blockIdx.x * 256 + threadIdx.x;
    if (i >= n) return;
    float4 p = pts[i];
    bool ok;
    int c = cell_of(p, ok);
    lin[i] = ok ? c : -1;
    bool isNew = false;
    if (ok && i < K) {
        int old = atomicMin(&first[c], i);
        isNew = (old == INF_SENTINEL);
    }
    u64 m = __ballot(isNew);
    if ((threadIdx.x & 63) == 0 && m != 0ull)
        atomicAdd(dcount, __popcll(m));
}

// K3: guard — if the prefix produced fewer than MAX_VOX distinct cells, the
// prefix bound is insufficient; claim the remaining points too (filtered
// atomicMin — exact under stale reads since first[] only decreases: a stale
// pass does a redundant atomic, a stale fail implies current <= i already).
// No-op dispatch (~2-3 us) in the common case.
__global__ __launch_bounds__(256) void guard(const float4* __restrict__ pts,
                                             int* __restrict__ first,
                                             const int* __restrict__ dcount,
                                             int K, int n) {
    if (*dcount >= MAX_VOX) return;
    for (int i = K + blockIdx.x * 256 + threadIdx.x; i < n;
         i += gridDim.x * 256) {
        float4 p = pts[i];
        bool ok;
        int c = cell_of(p, ok);
        if (ok && first[c] > i) atomicMin(&first[c], i);
    }
}

// K4: set bit first[c] in the index-space bitmap. Distinct cells have
// distinct first indices; words shared by ~3 cells -> low-contention atomicOr.
__global__ __launch_bounds__(256) void kMark(const int* __restrict__ first,
                                             u64* __restrict__ bits) {
    int c = blockIdx.x * 256 + threadIdx.x;
    if (c >= G_TOTAL) return;
    int f = first[c];
    if (f != INF_SENTINEL) atomicOr(&bits[f >> 6], 1ull << (f & 63));
}

// K5: per-word intra-block exclusive prefix (wordLocal) + per-block sums.
// One 64-bit word per thread, 256 words per block.
__global__ __launch_bounds__(256) void kScan(const u64* __restrict__ bits,
                                             unsigned* __restrict__ wordLocal,
                                             int* __restrict__ sums, int W) {
    __shared__ int wsum[4], wexc[4];
    int t = threadIdx.x;
    int wi = blockIdx.x * 256 + t;
    u64 mask = (wi < W) ? bits[wi] : 0ull;
    int v = __popcll(mask);
    int lane = t & 63, w = t >> 6;
    int x = v;
    for (int d = 1; d < 64; d <<= 1) {
        int y = __shfl_up(x, d, 64);
        if (lane >= d) x += y;
    }
    if (lane == 63) wsum[w] = x;
    __syncthreads();
    if (t == 0) {
        int a = 0;
        for (int j = 0; j < 4; j++) { wexc[j] = a; a += wsum[j]; }
        sums[blockIdx.x] = a;
    }
    __syncthreads();
    if (wi < W) wordLocal[wi] = (unsigned)(wexc[w] + x - v);
}

// K6: materialize rank PER CELL (one O(1) computation per claimed cell, so
// the 2M-point append pass does only ONE random read). Each block redundantly
// exclusive-scans the (<=256) block sums in LDS (~500B, L2-hot). Also writes
// cellOfRank and num_voxels (block 0) — replaces a separate scanB kernel.
__global__ __launch_bounds__(256) void kRank(const int* __restrict__ first,
                                             const u64* __restrict__ bits,
                                             const unsigned* __restrict__ wordLocal,
                                             const int* __restrict__ sums,
                                             int nbW,
                                             int* __restrict__ rank,
                                             int* __restrict__ cellOfRank,
                                             float* __restrict__ nvOut) {
    __shared__ int sExc[256];
    __shared__ int wsum[4], wexc[4];
    int t = threadIdx.x;
    int v = (t < nbW) ? sums[t] : 0;
    int lane = t & 63, w = t >> 6;
    int x = v;
    for (int d = 1; d < 64; d <<= 1) {
        int y = __shfl_up(x, d, 64);
        if (lane >= d) x += y;
    }
    if (lane == 63) wsum[w] = x;
    __syncthreads();
    if (t == 0) {
        int a = 0;
        for (int j = 0; j < 4; j++) { wexc[j] = a; a += wsum[j]; }
        if (blockIdx.x == 0) nvOut[0] = (float)(a < MAX_VOX ? a : MAX_VOX);
    }
    __syncthreads();
    sExc[t] = wexc[w] + x - v;
    __syncthreads();

    int c = blockIdx.x * 256 + t;
    if (c >= G_TOTAL) return;
    int f = first[c];
    if (f == INF_SENTINEL) return;
    int wf = f >> 6, b = f & 63;
    u64 lowmask = (b == 0) ? 0ull : ((~0ull) >> (64 - b));
    int vr = sExc[wf >> 8] + (int)wordLocal[wf] + __popcll(bits[wf] & lowmask);
    rank[c] = vr;
    if (vr < MAX_VOX) cellOfRank[vr] = c;
}

// K7: append pass — coalesced lin[i] + ONE random L2 read (rank[c]) + one
// atomic for the ~94K points landing in kept voxels. Unsigned compare so no
// conceivable rank value can produce a negative (OOB) vcount index.
__global__ __launch_bounds__(256) void kAppend(const int* __restrict__ lin,
                                               const int* __restrict__ rank,
                                               int* __restrict__ vcount,
                                               int* __restrict__ list, int n) {
    int i = blockIdx.x * 256 + threadIdx.x;
    if (i >= n) return;
    int c = lin[i];
    if (c < 0) return;
    int vr = rank[c];
    if ((unsigned)vr >= MAX_VOX) return;
    int pos = atomicAdd(&vcount[vr], 1) + 1;
    if (pos < CAP) list[vr * CAP + pos] = i;
}

// K8: 4 voxels per 256-thread block (one wave each). Counting-sort the
// collected indices (LDS broadcast reads), write all 32 slots + num_points
// + coors (so no d_out pre-memset is needed).
__global__ __launch_bounds__(256) void passF(const float4* __restrict__ pts,
                                             const int* __restrict__ vcount,
                                             const int* __restrict__ cellOfRank,
                                             const int* __restrict__ list,
                                             float4* __restrict__ voxOut,
                                             float* __restrict__ coorsOut,
                                             float* __restrict__ npOut) {
    __shared__ int s[4][CAP];
    __shared__ int slotPt[4][MAX_PTS];
    int w = threadIdx.x >> 6, lane = threadIdx.x & 63;
    int v = blockIdx.x * 4 + w;
    int cnt = vcount[v] + 1;
    int m = cnt < CAP ? cnt : CAP;
    s[w][lane] = (lane < m) ? list[v * CAP + lane] : 0x7FFFFFFF;
    if (lane < MAX_PTS) slotPt[w][lane] = -1;
    __syncthreads();
    int my = s[w][lane];
    int r = 0;
#pragma unroll
    for (int j = 0; j < CAP; j++) r += (s[w][j] < my) ? 1 : 0;  // broadcast
    if (lane < m && r < MAX_PTS) slotPt[w][r] = my;
    __syncthreads();
    if (lane < MAX_PTS) {
        int p = slotPt[w][lane];
        float4 val = make_float4(0.f, 0.f, 0.f, 0.f);
        if (p >= 0) val = pts[p];
        voxOut[(size_t)v * MAX_PTS + lane] = val;
    }
    if (lane == 0) {
        npOut[v] = (float)(cnt < MAX_PTS ? cnt : MAX_PTS);
        int cell = cellOfRank[v];
        if (cell < 0) {
            coorsOut[3 * v + 0] = -1.0f;
            coorsOut[3 * v + 1] = -1.0f;
            coorsOut[3 * v + 2] = -1.0f;
        } else {
            coorsOut[3 * v + 0] = 0.0f;  // cz (GZ==1)
            coorsOut[3 * v + 1] = (float)(cell / GX);
            coorsOut[3 * v + 2] = (float)(cell % GX);
        }
    }
}

extern "C" void kernel_launch(void* const* d_in, const int* in_sizes, int n_in,
                              void* d_out, int out_size, void* d_ws, size_t ws_size,
                              hipStream_t stream) {
    const float4* pts = (const float4*)d_in[0];
    int n = in_sizes[0] / 4;    // 2,000,000
    int W = (n + 63) >> 6;      // 31250 bitmap words
    int nbW = (W + 255) / 256;  // 123
    int K = PREFIX_K < n ? PREFIX_K : n;

    char* ws = (char*)d_ws;
    size_t off = 0;
    auto alloc = [&](size_t bytes) -> void* {
        void* p = (void*)(ws + off);
        off = (off + bytes + 255) & ~(size_t)255;
        return p;
    };
    int* first = (int*)alloc((size_t)G_TOTAL * 4);
    int* lin = (int*)alloc((size_t)n * 4);
    u64* bits = (u64*)alloc((size_t)W * 8);
    unsigned* wordLocal = (unsigned*)alloc((size_t)W * 4);
    int* sums = (int*)alloc(256 * 4);
    int* rank = (int*)alloc((size_t)G_TOTAL * 4);
    int* vcount = (int*)alloc((size_t)MAX_VOX * 4);
    int* cellOfRank = (int*)alloc((size_t)MAX_VOX * 4);
    int* dcount = (int*)alloc(256 * 4);
    int* list = (int*)alloc((size_t)MAX_VOX * CAP * 4);
    (void)ws_size;
    (void)n_in;
    (void)out_size;

    float* out = (float*)d_out;
    float4* voxOut = (float4*)out;                          // 20000*32*4
    float* coorsOut = out + (size_t)MAX_VOX * MAX_PTS * 4;  // 20000*3
    float* npOut = coorsOut + (size_t)MAX_VOX * 3;          // 20000
    float* nvOut = npOut + MAX_VOX;                         // 1

    int nbP = (n + 255) / 256;        // 7813
    int nbC = (G_TOTAL + 255) / 256;  // 837

    kInit<<<nbC, 256, 0, stream>>>(first, rank, bits, vcount, cellOfRank,
                                   dcount, W);
    kPoints<<<nbP, 256, 0, stream>>>(pts, lin, first, dcount, K, n);
    guard<<<1024, 256, 0, stream>>>(pts, first, dcount, K, n);
    kMark<<<nbC, 256, 0, stream>>>(first, bits);
    kScan<<<nbW, 256, 0, stream>>>(bits, wordLocal, sums, W);
    kRank<<<nbC, 256, 0, stream>>>(first, bits, wordLocal, sums, nbW, rank,
                                   cellOfRank, nvOut);
    kAppend<<<nbP, 256, 0, stream>>>(lin, rank, vcount, list, n);
    passF<<<MAX_VOX / 4, 256, 0, stream>>>(pts, vcount, cellOfRank, list,
                                           voxOut, coorsOut, npOut);
}

// Round 6
// 127.913 us; speedup vs baseline: 1.2449x; 1.2449x over previous
//
#include <hip/hip_runtime.h>

#define GX 432
#define GY 496
#define G_TOTAL (GX * GY) /* 214272, GZ=1 */
#define MAX_PTS 32
#define MAX_VOX 20000
#define CAP 64
#define INF_SENTINEL 0x7F7F7F7F
#define PREFIX_K 262144 /* ~133k in-range claims -> ~99k distinct cells >> 20000 */

typedef unsigned long long u64;

// IEEE float32 ops exactly matching the reference:
// c = floor((p - lo)/vs), lo = [0, -39.68, -3], vs = [.16,.16,4].
__device__ __forceinline__ int cell_of(float4 p, bool& ok) {
    float fx = floorf((p.x - 0.0f) / 0.16f);
    float fy = floorf((p.y + 39.68f) / 0.16f);
    float fz = floorf((p.z + 3.0f) / 4.0f);
    int cx = (int)fx, cy = (int)fy, cz = (int)fz;
    ok = (cx >= 0 && cx < GX && cy >= 0 && cy < GY && cz == 0);
    return cy * GX + cx;
}

// K1: fused initialization of every table consumed downstream.
// rank[] MUST be inited to INF: under the prefix heuristic, cells whose
// first point is >= K are never ranked, but kAppend reads rank[c] for any
// in-range cell (round-4 crash lesson). INF filters them.
__global__ __launch_bounds__(256) void kInit(int* __restrict__ first,
                                             int* __restrict__ rank,
                                             u64* __restrict__ bits,
                                             int* __restrict__ vcount,
                                             int* __restrict__ cellOfRank,
                                             int* __restrict__ dcount, int W) {
    int i = blockIdx.x * 256 + threadIdx.x;
    if (i < G_TOTAL) { first[i] = INF_SENTINEL; rank[i] = INF_SENTINEL; }
    if (i < W) bits[i] = 0ull;
    if (i < MAX_VOX) { vcount[i] = -1; cellOfRank[i] = -1; }
    if (i == 0) *dcount = 0;
}

// K2: point pass, 4 points/thread (1024/block) for MLP=4 (round-5 lesson:
// MLP=1 makes this pass latency-bound at ~44-57 us despite ~7 us of traffic).
// Loads are unconditional via clamped index so all 4 issue back-to-back.
// atomicMin is fire-and-forget (no return use — the round-5 ballot fusion
// cost +13 us) and only for the prefix i < K. Blocks 0..255 are the prefix.
__global__ __launch_bounds__(256) void kPoints(const float4* __restrict__ pts,
                                               int* __restrict__ lin,
                                               int* __restrict__ first,
                                               int K, int n) {
    int i0 = blockIdx.x * 1024 + threadIdx.x;
    int i1 = i0 + 256, i2 = i0 + 512, i3 = i0 + 768;
    int m = n - 1;
    float4 p0 = pts[i0 < n ? i0 : m];
    float4 p1 = pts[i1 < n ? i1 : m];
    float4 p2 = pts[i2 < n ? i2 : m];
    float4 p3 = pts[i3 < n ? i3 : m];
    bool k0, k1, k2, k3;
    int c0 = cell_of(p0, k0);
    int c1 = cell_of(p1, k1);
    int c2 = cell_of(p2, k2);
    int c3 = cell_of(p3, k3);
    if (i0 < n) lin[i0] = k0 ? c0 : -1;
    if (i1 < n) lin[i1] = k1 ? c1 : -1;
    if (i2 < n) lin[i2] = k2 ? c2 : -1;
    if (i3 < n) lin[i3] = k3 ? c3 : -1;
    if (k0 && i0 < K) atomicMin(&first[c0], i0);
    if (k1 && i1 < K) atomicMin(&first[c1], i1);
    if (k2 && i2 < K) atomicMin(&first[c2], i2);
    if (k3 && i3 < K) atomicMin(&first[c3], i3);
}

// K3: count distinct cells claimed by the prefix (one L2-resident sweep of
// first[]; separate kernel — fusing the count into kPoints via atomicMin
// return was the round-5 regression).
__global__ __launch_bounds__(256) void countD(const int* __restrict__ first,
                                              int* __restrict__ dcount) {
    __shared__ int wsh[4];
    int c = blockIdx.x * 256 + threadIdx.x;
    int have = (c < G_TOTAL && first[c] != INF_SENTINEL) ? 1 : 0;
    for (int d = 32; d >= 1; d >>= 1) have += __shfl_down(have, d, 64);
    if ((threadIdx.x & 63) == 0) wsh[threadIdx.x >> 6] = have;
    __syncthreads();
    if (threadIdx.x == 0)
        atomicAdd(dcount, wsh[0] + wsh[1] + wsh[2] + wsh[3]);
}

// K4: guard — if the prefix produced fewer than MAX_VOX distinct cells,
// claim the remaining points too (filtered atomicMin — exact under stale
// reads since first[] only decreases). Runs BEFORE kMark, so the bitmap is
// always built from the final first[] (no bit-repair races). No-op dispatch
// in the common case.
__global__ __launch_bounds__(256) void guard(const float4* __restrict__ pts,
                                             int* __restrict__ first,
                                             const int* __restrict__ dcount,
                                             int K, int n) {
    if (*dcount >= MAX_VOX) return;
    for (int i = K + blockIdx.x * 256 + threadIdx.x; i < n;
         i += gridDim.x * 256) {
        float4 p = pts[i];
        bool ok;
        int c = cell_of(p, ok);
        if (ok && first[c] > i) atomicMin(&first[c], i);
    }
}

// K5: set bit first[c] in the index-space bitmap. Distinct cells have
// distinct first indices; words shared by ~3 cells -> low-contention atomicOr.
__global__ __launch_bounds__(256) void kMark(const int* __restrict__ first,
                                             u64* __restrict__ bits) {
    int c = blockIdx.x * 256 + threadIdx.x;
    if (c >= G_TOTAL) return;
    int f = first[c];
    if (f != INF_SENTINEL) atomicOr(&bits[f >> 6], 1ull << (f & 63));
}

// K6: per-word intra-block exclusive prefix (wordLocal) + per-block sums.
__global__ __launch_bounds__(256) void kScan(const u64* __restrict__ bits,
                                             unsigned* __restrict__ wordLocal,
                                             int* __restrict__ sums, int W) {
    __shared__ int wsum[4], wexc[4];
    int t = threadIdx.x;
    int wi = blockIdx.x * 256 + t;
    u64 mask = (wi < W) ? bits[wi] : 0ull;
    int v = __popcll(mask);
    int lane = t & 63, w = t >> 6;
    int x = v;
    for (int d = 1; d < 64; d <<= 1) {
        int y = __shfl_up(x, d, 64);
        if (lane >= d) x += y;
    }
    if (lane == 63) wsum[w] = x;
    __syncthreads();
    if (t == 0) {
        int a = 0;
        for (int j = 0; j < 4; j++) { wexc[j] = a; a += wsum[j]; }
        sums[blockIdx.x] = a;
    }
    __syncthreads();
    if (wi < W) wordLocal[wi] = (unsigned)(wexc[w] + x - v);
}

// K7: materialize rank PER CELL (so the 2M-point append pass does only ONE
// random read). Each block redundantly exclusive-scans the (<=256) block
// sums in LDS. Also writes cellOfRank and num_voxels (block 0).
__global__ __launch_bounds__(256) void kRank(const int* __restrict__ first,
                                             const u64* __restrict__ bits,
                                             const unsigned* __restrict__ wordLocal,
                                             const int* __restrict__ sums,
                                             int nbW,
                                             int* __restrict__ rank,
                                             int* __restrict__ cellOfRank,
                                             float* __restrict__ nvOut) {
    __shared__ int sExc[256];
    __shared__ int wsum[4], wexc[4];
    int t = threadIdx.x;
    int v = (t < nbW) ? sums[t] : 0;
    int lane = t & 63, w = t >> 6;
    int x = v;
    for (int d = 1; d < 64; d <<= 1) {
        int y = __shfl_up(x, d, 64);
        if (lane >= d) x += y;
    }
    if (lane == 63) wsum[w] = x;
    __syncthreads();
    if (t == 0) {
        int a = 0;
        for (int j = 0; j < 4; j++) { wexc[j] = a; a += wsum[j]; }
        if (blockIdx.x == 0) nvOut[0] = (float)(a < MAX_VOX ? a : MAX_VOX);
    }
    __syncthreads();
    sExc[t] = wexc[w] + x - v;
    __syncthreads();

    int c = blockIdx.x * 256 + t;
    if (c >= G_TOTAL) return;
    int f = first[c];
    if (f == INF_SENTINEL) return;
    int wf = f >> 6, b = f & 63;
    u64 lowmask = (b == 0) ? 0ull : ((~0ull) >> (64 - b));
    int vr = sExc[wf >> 8] + (int)wordLocal[wf] + __popcll(bits[wf] & lowmask);
    rank[c] = vr;
    if (vr < MAX_VOX) cellOfRank[vr] = c;
}

// K8: append pass, 4 points/thread: int4 load of lin (coalesced 16B/lane)
// + 4 UNCONDITIONALLY-issued rank loads (select after load, not branch
// around load — keeps MLP=4 on the random-read latency chain). Unsigned
// compare so no rank value can index vcount negatively.
__global__ __launch_bounds__(256) void kAppend(const int* __restrict__ lin,
                                               const int* __restrict__ rank,
                                               int* __restrict__ vcount,
                                               int* __restrict__ list, int n) {
    int gid = blockIdx.x * 256 + threadIdx.x;
    int nq = n >> 2;
    if (gid >= nq) return;
    int4 l = ((const int4*)lin)[gid];
    int a0 = l.x >= 0 ? l.x : 0;
    int a1 = l.y >= 0 ? l.y : 0;
    int a2 = l.z >= 0 ? l.z : 0;
    int a3 = l.w >= 0 ? l.w : 0;
    int r0 = rank[a0], r1 = rank[a1], r2 = rank[a2], r3 = rank[a3];
    r0 = l.x >= 0 ? r0 : INF_SENTINEL;
    r1 = l.y >= 0 ? r1 : INF_SENTINEL;
    r2 = l.z >= 0 ? r2 : INF_SENTINEL;
    r3 = l.w >= 0 ? r3 : INF_SENTINEL;
    int i0 = gid * 4;
#pragma unroll
    for (int j = 0; j < 4; j++) {
        int vr = j == 0 ? r0 : j == 1 ? r1 : j == 2 ? r2 : r3;
        if ((unsigned)vr >= MAX_VOX) continue;
        int pos = atomicAdd(&vcount[vr], 1) + 1;
        if (pos < CAP) list[vr * CAP + pos] = i0 + j;
    }
    // scalar tail (n % 4), executed once
    if (gid == 0) {
        for (int i = nq << 2; i < n; i++) {
            int c = lin[i];
            if (c < 0) continue;
            int vr = rank[c];
            if ((unsigned)vr >= MAX_VOX) continue;
            int pos = atomicAdd(&vcount[vr], 1) + 1;
            if (pos < CAP) list[vr * CAP + pos] = i;
        }
    }
}

// K9: 4 voxels per 256-thread block (one wave each). Counting-sort the
// collected indices (LDS broadcast reads), write all 32 slots + num_points
// + coors (so no d_out pre-memset is needed).
__global__ __launch_bounds__(256) void passF(const float4* __restrict__ pts,
                                             const int* __restrict__ vcount,
                                             const int* __restrict__ cellOfRank,
                                             const int* __restrict__ list,
                                             float4* __restrict__ voxOut,
                                             float* __restrict__ coorsOut,
                                             float* __restrict__ npOut) {
    __shared__ int s[4][CAP];
    __shared__ int slotPt[4][MAX_PTS];
    int w = threadIdx.x >> 6, lane = threadIdx.x & 63;
    int v = blockIdx.x * 4 + w;
    int cnt = vcount[v] + 1;
    int m = cnt < CAP ? cnt : CAP;
    s[w][lane] = (lane < m) ? list[v * CAP + lane] : 0x7FFFFFFF;
    if (lane < MAX_PTS) slotPt[w][lane] = -1;
    __syncthreads();
    int my = s[w][lane];
    int r = 0;
#pragma unroll
    for (int j = 0; j < CAP; j++) r += (s[w][j] < my) ? 1 : 0;  // broadcast
    if (lane < m && r < MAX_PTS) slotPt[w][r] = my;
    __syncthreads();
    if (lane < MAX_PTS) {
        int p = slotPt[w][lane];
        float4 val = make_float4(0.f, 0.f, 0.f, 0.f);
        if (p >= 0) val = pts[p];
        voxOut[(size_t)v * MAX_PTS + lane] = val;
    }
    if (lane == 0) {
        npOut[v] = (float)(cnt < MAX_PTS ? cnt : MAX_PTS);
        int cell = cellOfRank[v];
        if (cell < 0) {
            coorsOut[3 * v + 0] = -1.0f;
            coorsOut[3 * v + 1] = -1.0f;
            coorsOut[3 * v + 2] = -1.0f;
        } else {
            coorsOut[3 * v + 0] = 0.0f;  // cz (GZ==1)
            coorsOut[3 * v + 1] = (float)(cell / GX);
            coorsOut[3 * v + 2] = (float)(cell % GX);
        }
    }
}

extern "C" void kernel_launch(void* const* d_in, const int* in_sizes, int n_in,
                              void* d_out, int out_size, void* d_ws, size_t ws_size,
                              hipStream_t stream) {
    const float4* pts = (const float4*)d_in[0];
    int n = in_sizes[0] / 4;    // 2,000,000
    int W = (n + 63) >> 6;      // 31250 bitmap words
    int nbW = (W + 255) / 256;  // 123
    int K = PREFIX_K < n ? PREFIX_K : n;

    char* ws = (char*)d_ws;
    size_t off = 0;
    auto alloc = [&](size_t bytes) -> void* {
        void* p = (void*)(ws + off);
        off = (off + bytes + 255) & ~(size_t)255;
        return p;
    };
    int* first = (int*)alloc((size_t)G_TOTAL * 4);
    int* lin = (int*)alloc((size_t)n * 4);
    u64* bits = (u64*)alloc((size_t)W * 8);
    unsigned* wordLocal = (unsigned*)alloc((size_t)W * 4);
    int* sums = (int*)alloc(256 * 4);
    int* rank = (int*)alloc((size_t)G_TOTAL * 4);
    int* vcount = (int*)alloc((size_t)MAX_VOX * 4);
    int* cellOfRank = (int*)alloc((size_t)MAX_VOX * 4);
    int* dcount = (int*)alloc(256 * 4);
    int* list = (int*)alloc((size_t)MAX_VOX * CAP * 4);
    (void)ws_size;
    (void)n_in;
    (void)out_size;

    float* out = (float*)d_out;
    float4* voxOut = (float4*)out;                          // 20000*32*4
    float* coorsOut = out + (size_t)MAX_VOX * MAX_PTS * 4;  // 20000*3
    float* npOut = coorsOut + (size_t)MAX_VOX * 3;          // 20000
    float* nvOut = npOut + MAX_VOX;                         // 1

    int nbP4 = (n + 1023) / 1024;     // 1954 (4 pts/thread)
    int nbC = (G_TOTAL + 255) / 256;  // 837
    int nbA = ((n >> 2) + 255) / 256; // 1954 (int4 per thread)

    kInit<<<nbC, 256, 0, stream>>>(first, rank, bits, vcount, cellOfRank,
                                   dcount, W);
    kPoints<<<nbP4, 256, 0, stream>>>(pts, lin, first, K, n);
    countD<<<nbC, 256, 0, stream>>>(first, dcount);
    guard<<<1024, 256, 0, stream>>>(pts, first, dcount, K, n);
    kMark<<<nbC, 256, 0, stream>>>(first, bits);
    kScan<<<nbW, 256, 0, stream>>>(bits, wordLocal, sums, W);
    kRank<<<nbC, 256, 0, stream>>>(first, bits, wordLocal, sums, nbW, rank,
                                   cellOfRank, nvOut);
    kAppend<<<nbA, 256, 0, stream>>>(lin, rank, vcount, list, n);
    passF<<<MAX_VOX / 4, 256, 0, stream>>>(pts, vcount, cellOfRank, list,
                                           voxOut, coorsOut, npOut);
}

// Round 7
// 119.741 us; speedup vs baseline: 1.3298x; 1.0682x over previous
//
#include <hip/hip_runtime.h>

#define GX 432
#define GY 496
#define G_TOTAL (GX * GY) /* 214272, GZ=1 */
#define MAX_PTS 32
#define MAX_VOX 20000
#define CAP 64
#define INF_SENTINEL 0x7F7F7F7F
#define PREFIX_K 262144 /* ~131k in-range claims -> ~97k distinct cells >> 20000 */

typedef unsigned long long u64;

// IEEE float32 ops exactly matching the reference:
// c = floor((p - lo)/vs), lo = [0, -39.68, -3], vs = [.16,.16,4].
__device__ __forceinline__ int cell_of(float4 p, bool& ok) {
    float fx = floorf((p.x - 0.0f) / 0.16f);
    float fy = floorf((p.y + 39.68f) / 0.16f);
    float fz = floorf((p.z + 3.0f) / 4.0f);
    int cx = (int)fx, cy = (int)fy, cz = (int)fz;
    ok = (cx >= 0 && cx < GX && cy >= 0 && cy < GY && cz == 0);
    return cy * GX + cx;
}

// K1: fused initialization of every table consumed downstream.
// rank[] MUST be inited to INF: under the prefix heuristic, cells whose
// first point is >= K are never ranked, but kAppend reads rank[c] for any
// in-range cell (round-4 crash lesson). INF filters them.
__global__ __launch_bounds__(256) void kInit(int* __restrict__ first,
                                             int* __restrict__ rank,
                                             u64* __restrict__ bits,
                                             int* __restrict__ vcount,
                                             int* __restrict__ cellOfRank,
                                             int* __restrict__ dcount, int W) {
    int i = blockIdx.x * 256 + threadIdx.x;
    if (i < G_TOTAL) { first[i] = INF_SENTINEL; rank[i] = INF_SENTINEL; }
    if (i < W) bits[i] = 0ull;
    if (i < MAX_VOX) { vcount[i] = -1; cellOfRank[i] = -1; }
    if (i == 0) *dcount = 0;
}

// K2: PREFIX-ONLY point pass (lin[] eliminated — round-6 insight: kAppend
// recomputes cells bitwise-identically from pts, so the full 2M sweep here
// was redundant). 4 points/thread for MLP=4 (round-5 lesson), fire-and-
// forget atomicMin (round-5: using the return value cost +13 us).
// Grid covers exactly K points.
__global__ __launch_bounds__(256) void kPoints(const float4* __restrict__ pts,
                                               int* __restrict__ first,
                                               int K) {
    int i0 = blockIdx.x * 1024 + threadIdx.x;
    int i1 = i0 + 256, i2 = i0 + 512, i3 = i0 + 768;
    int m = K - 1;
    float4 p0 = pts[i0 < K ? i0 : m];
    float4 p1 = pts[i1 < K ? i1 : m];
    float4 p2 = pts[i2 < K ? i2 : m];
    float4 p3 = pts[i3 < K ? i3 : m];
    bool k0, k1, k2, k3;
    int c0 = cell_of(p0, k0);
    int c1 = cell_of(p1, k1);
    int c2 = cell_of(p2, k2);
    int c3 = cell_of(p3, k3);
    if (k0 && i0 < K) atomicMin(&first[c0], i0);
    if (k1 && i1 < K) atomicMin(&first[c1], i1);
    if (k2 && i2 < K) atomicMin(&first[c2], i2);
    if (k3 && i3 < K) atomicMin(&first[c3], i3);
}

// K3: count distinct cells claimed by the prefix. int4 sweep (G_TOTAL%4==0),
// 4 cells/thread; one L2-resident 857KB read. Separate kernel — fusing the
// count into kPoints via atomicMin return was the round-5 regression.
__global__ __launch_bounds__(256) void countD(const int* __restrict__ first,
                                              int* __restrict__ dcount) {
    __shared__ int wsh[4];
    int q = blockIdx.x * 256 + threadIdx.x;
    int have = 0;
    if (q < (G_TOTAL / 4)) {
        int4 f = ((const int4*)first)[q];
        have = (f.x != INF_SENTINEL) + (f.y != INF_SENTINEL) +
               (f.z != INF_SENTINEL) + (f.w != INF_SENTINEL);
    }
    for (int d = 32; d >= 1; d >>= 1) have += __shfl_down(have, d, 64);
    if ((threadIdx.x & 63) == 0) wsh[threadIdx.x >> 6] = have;
    __syncthreads();
    if (threadIdx.x == 0)
        atomicAdd(dcount, wsh[0] + wsh[1] + wsh[2] + wsh[3]);
}

// K4: guard — if the prefix produced fewer than MAX_VOX distinct cells,
// claim the remaining points too (filtered atomicMin — exact under stale
// reads since first[] only decreases). Runs BEFORE kMark, so the bitmap is
// always built from the final first[]. No-op dispatch in the common case.
__global__ __launch_bounds__(256) void guard(const float4* __restrict__ pts,
                                             int* __restrict__ first,
                                             const int* __restrict__ dcount,
                                             int K, int n) {
    if (*dcount >= MAX_VOX) return;
    for (int i = K + blockIdx.x * 256 + threadIdx.x; i < n;
         i += gridDim.x * 256) {
        float4 p = pts[i];
        bool ok;
        int c = cell_of(p, ok);
        if (ok && first[c] > i) atomicMin(&first[c], i);
    }
}

// K5: set bit first[c] in the index-space bitmap. Distinct cells have
// distinct first indices; words shared by ~3 cells -> low-contention atomicOr.
__global__ __launch_bounds__(256) void kMark(const int* __restrict__ first,
                                             u64* __restrict__ bits) {
    int c = blockIdx.x * 256 + threadIdx.x;
    if (c >= G_TOTAL) return;
    int f = first[c];
    if (f != INF_SENTINEL) atomicOr(&bits[f >> 6], 1ull << (f & 63));
}

// K6: per-word intra-block exclusive prefix (wordLocal) + per-block sums.
__global__ __launch_bounds__(256) void kScan(const u64* __restrict__ bits,
                                             unsigned* __restrict__ wordLocal,
                                             int* __restrict__ sums, int W) {
    __shared__ int wsum[4], wexc[4];
    int t = threadIdx.x;
    int wi = blockIdx.x * 256 + t;
    u64 mask = (wi < W) ? bits[wi] : 0ull;
    int v = __popcll(mask);
    int lane = t & 63, w = t >> 6;
    int x = v;
    for (int d = 1; d < 64; d <<= 1) {
        int y = __shfl_up(x, d, 64);
        if (lane >= d) x += y;
    }
    if (lane == 63) wsum[w] = x;
    __syncthreads();
    if (t == 0) {
        int a = 0;
        for (int j = 0; j < 4; j++) { wexc[j] = a; a += wsum[j]; }
        sums[blockIdx.x] = a;
    }
    __syncthreads();
    if (wi < W) wordLocal[wi] = (unsigned)(wexc[w] + x - v);
}

// K7: materialize rank PER CELL (so the 2M-point append pass does only ONE
// random read). Each block redundantly exclusive-scans the (<=256) block
// sums in LDS. Also writes cellOfRank and num_voxels (block 0).
__global__ __launch_bounds__(256) void kRank(const int* __restrict__ first,
                                             const u64* __restrict__ bits,
                                             const unsigned* __restrict__ wordLocal,
                                             const int* __restrict__ sums,
                                             int nbW,
                                             int* __restrict__ rank,
                                             int* __restrict__ cellOfRank,
                                             float* __restrict__ nvOut) {
    __shared__ int sExc[256];
    __shared__ int wsum[4], wexc[4];
    int t = threadIdx.x;
    int v = (t < nbW) ? sums[t] : 0;
    int lane = t & 63, w = t >> 6;
    int x = v;
    for (int d = 1; d < 64; d <<= 1) {
        int y = __shfl_up(x, d, 64);
        if (lane >= d) x += y;
    }
    if (lane == 63) wsum[w] = x;
    __syncthreads();
    if (t == 0) {
        int a = 0;
        for (int j = 0; j < 4; j++) { wexc[j] = a; a += wsum[j]; }
        if (blockIdx.x == 0) nvOut[0] = (float)(a < MAX_VOX ? a : MAX_VOX);
    }
    __syncthreads();
    sExc[t] = wexc[w] + x - v;
    __syncthreads();

    int c = blockIdx.x * 256 + t;
    if (c >= G_TOTAL) return;
    int f = first[c];
    if (f == INF_SENTINEL) return;
    int wf = f >> 6, b = f & 63;
    u64 lowmask = (b == 0) ? 0ull : ((~0ull) >> (64 - b));
    int vr = sExc[wf >> 8] + (int)wordLocal[wf] + __popcll(bits[wf] & lowmask);
    rank[c] = vr;
    if (vr < MAX_VOX) cellOfRank[vr] = c;
}

// K8: append pass, 4 consecutive points/thread (64B contiguous per lane).
// Cells recomputed from pts (bitwise-identical to kPoints; pts L3-resident)
// — no lin[] array. rank loads issued UNCONDITIONALLY via clamped index
// (select after load, MLP=4 on the 2-level pts->rank chain). Unsigned
// compare so no rank value can index vcount negatively (round-4 lesson).
__global__ __launch_bounds__(256) void kAppend(const float4* __restrict__ pts,
                                               const int* __restrict__ rank,
                                               int* __restrict__ vcount,
                                               int* __restrict__ list, int n) {
    int gid = blockIdx.x * 256 + threadIdx.x;
    int nq = n >> 2;
    if (gid < nq) {
        int base = gid * 4;
        float4 p0 = pts[base + 0];
        float4 p1 = pts[base + 1];
        float4 p2 = pts[base + 2];
        float4 p3 = pts[base + 3];
        bool k0, k1, k2, k3;
        int c0 = cell_of(p0, k0);
        int c1 = cell_of(p1, k1);
        int c2 = cell_of(p2, k2);
        int c3 = cell_of(p3, k3);
        int r0 = rank[k0 ? c0 : 0];
        int r1 = rank[k1 ? c1 : 0];
        int r2 = rank[k2 ? c2 : 0];
        int r3 = rank[k3 ? c3 : 0];
        r0 = k0 ? r0 : INF_SENTINEL;
        r1 = k1 ? r1 : INF_SENTINEL;
        r2 = k2 ? r2 : INF_SENTINEL;
        r3 = k3 ? r3 : INF_SENTINEL;
#pragma unroll
        for (int j = 0; j < 4; j++) {
            int vr = j == 0 ? r0 : j == 1 ? r1 : j == 2 ? r2 : r3;
            if ((unsigned)vr >= MAX_VOX) continue;
            int pos = atomicAdd(&vcount[vr], 1) + 1;
            if (pos < CAP) list[vr * CAP + pos] = base + j;
        }
    }
    // scalar tail (n % 4), executed once
    if (gid == 0) {
        for (int i = nq << 2; i < n; i++) {
            float4 p = pts[i];
            bool ok;
            int c = cell_of(p, ok);
            if (!ok) continue;
            int vr = rank[c];
            if ((unsigned)vr >= MAX_VOX) continue;
            int pos = atomicAdd(&vcount[vr], 1) + 1;
            if (pos < CAP) list[vr * CAP + pos] = i;
        }
    }
}

// K9: 4 voxels per 256-thread block (one wave each). Counting-sort the
// collected indices (LDS broadcast reads), write all 32 slots + num_points
// + coors (so no d_out pre-memset is needed).
__global__ __launch_bounds__(256) void passF(const float4* __restrict__ pts,
                                             const int* __restrict__ vcount,
                                             const int* __restrict__ cellOfRank,
                                             const int* __restrict__ list,
                                             float4* __restrict__ voxOut,
                                             float* __restrict__ coorsOut,
                                             float* __restrict__ npOut) {
    __shared__ int s[4][CAP];
    __shared__ int slotPt[4][MAX_PTS];
    int w = threadIdx.x >> 6, lane = threadIdx.x & 63;
    int v = blockIdx.x * 4 + w;
    int cnt = vcount[v] + 1;
    int m = cnt < CAP ? cnt : CAP;
    s[w][lane] = (lane < m) ? list[v * CAP + lane] : 0x7FFFFFFF;
    if (lane < MAX_PTS) slotPt[w][lane] = -1;
    __syncthreads();
    int my = s[w][lane];
    int r = 0;
#pragma unroll
    for (int j = 0; j < CAP; j++) r += (s[w][j] < my) ? 1 : 0;  // broadcast
    if (lane < m && r < MAX_PTS) slotPt[w][r] = my;
    __syncthreads();
    if (lane < MAX_PTS) {
        int p = slotPt[w][lane];
        float4 val = make_float4(0.f, 0.f, 0.f, 0.f);
        if (p >= 0) val = pts[p];
        voxOut[(size_t)v * MAX_PTS + lane] = val;
    }
    if (lane == 0) {
        npOut[v] = (float)(cnt < MAX_PTS ? cnt : MAX_PTS);
        int cell = cellOfRank[v];
        if (cell < 0) {
            coorsOut[3 * v + 0] = -1.0f;
            coorsOut[3 * v + 1] = -1.0f;
            coorsOut[3 * v + 2] = -1.0f;
        } else {
            coorsOut[3 * v + 0] = 0.0f;  // cz (GZ==1)
            coorsOut[3 * v + 1] = (float)(cell / GX);
            coorsOut[3 * v + 2] = (float)(cell % GX);
        }
    }
}

extern "C" void kernel_launch(void* const* d_in, const int* in_sizes, int n_in,
                              void* d_out, int out_size, void* d_ws, size_t ws_size,
                              hipStream_t stream) {
    const float4* pts = (const float4*)d_in[0];
    int n = in_sizes[0] / 4;    // 2,000,000
    int W = (n + 63) >> 6;      // 31250 bitmap words
    int nbW = (W + 255) / 256;  // 123
    int K = PREFIX_K < n ? PREFIX_K : n;

    char* ws = (char*)d_ws;
    size_t off = 0;
    auto alloc = [&](size_t bytes) -> void* {
        void* p = (void*)(ws + off);
        off = (off + bytes + 255) & ~(size_t)255;
        return p;
    };
    int* first = (int*)alloc((size_t)G_TOTAL * 4);
    u64* bits = (u64*)alloc((size_t)W * 8);
    unsigned* wordLocal = (unsigned*)alloc((size_t)W * 4);
    int* sums = (int*)alloc(256 * 4);
    int* rank = (int*)alloc((size_t)G_TOTAL * 4);
    int* vcount = (int*)alloc((size_t)MAX_VOX * 4);
    int* cellOfRank = (int*)alloc((size_t)MAX_VOX * 4);
    int* dcount = (int*)alloc(256 * 4);
    int* list = (int*)alloc((size_t)MAX_VOX * CAP * 4);
    (void)ws_size;
    (void)n_in;
    (void)out_size;

    float* out = (float*)d_out;
    float4* voxOut = (float4*)out;                          // 20000*32*4
    float* coorsOut = out + (size_t)MAX_VOX * MAX_PTS * 4;  // 20000*3
    float* npOut = coorsOut + (size_t)MAX_VOX * 3;          // 20000
    float* nvOut = npOut + MAX_VOX;                         // 1

    int nbK = (K + 1023) / 1024;       // 256 (prefix only, 4 pts/thread)
    int nbC = (G_TOTAL + 255) / 256;   // 837
    int nbC4 = (G_TOTAL / 4 + 255) / 256;  // 210
    int nbA = ((n >> 2) + 255) / 256;  // 1954 (4 pts/thread)

    kInit<<<nbC, 256, 0, stream>>>(first, rank, bits, vcount, cellOfRank,
                                   dcount, W);
    kPoints<<<nbK, 256, 0, stream>>>(pts, first, K);
    countD<<<nbC4, 256, 0, stream>>>(first, dcount);
    guard<<<1024, 256, 0, stream>>>(pts, first, dcount, K, n);
    kMark<<<nbC, 256, 0, stream>>>(first, bits);
    kScan<<<nbW, 256, 0, stream>>>(bits, wordLocal, sums, W);
    kRank<<<nbC, 256, 0, stream>>>(first, bits, wordLocal, sums, nbW, rank,
                                   cellOfRank, nvOut);
    kAppend<<<nbA, 256, 0, stream>>>(pts, rank, vcount, list, n);
    passF<<<MAX_VOX / 4, 256, 0, stream>>>(pts, vcount, cellOfRank, list,
                                           voxOut, coorsOut, npOut);
}

// Round 8
// 117.871 us; speedup vs baseline: 1.3509x; 1.0159x over previous
//
#include <hip/hip_runtime.h>

#define GX 432
#define GY 496
#define G_TOTAL (GX * GY) /* 214272, GZ=1 */
#define MAX_PTS 32
#define MAX_VOX 20000
#define CAP 64
#define INF_SENTINEL 0x7F7F7F7F
#define PREFIX_K 262144 /* ~131k in-range claims -> ~97k distinct cells >> 20000 */

typedef unsigned long long u64;

// IEEE float32 ops exactly matching the reference:
// c = floor((p - lo)/vs), lo = [0, -39.68, -3], vs = [.16,.16,4].
__device__ __forceinline__ int cell_of(float4 p, bool& ok) {
    float fx = floorf((p.x - 0.0f) / 0.16f);
    float fy = floorf((p.y + 39.68f) / 0.16f);
    float fz = floorf((p.z + 3.0f) / 4.0f);
    int cx = (int)fx, cy = (int)fy, cz = (int)fz;
    ok = (cx >= 0 && cx < GX && cy >= 0 && cy < GY && cz == 0);
    return cy * GX + cx;
}

// K1: fused initialization, int4-vectorized (G_TOTAL%4==0, MAX_VOX%4==0).
// rank[] MUST be inited to INF: under the prefix heuristic, cells whose
// first point is >= K are never ranked, but kAppend reads rank[c] for any
// in-range cell (round-4 crash lesson). dcount[0]=distinct count,
// dcount[1]=blocks-done counter for the last-block pattern.
__global__ __launch_bounds__(256) void kInit(int* __restrict__ first,
                                             int* __restrict__ rank,
                                             u64* __restrict__ bits,
                                             int* __restrict__ vcount,
                                             int* __restrict__ cellOfRank,
                                             int* __restrict__ dcount, int W) {
    int i = blockIdx.x * 256 + threadIdx.x;
    const int4 inf4 = make_int4(INF_SENTINEL, INF_SENTINEL, INF_SENTINEL,
                                INF_SENTINEL);
    const int4 m14 = make_int4(-1, -1, -1, -1);
    if (i < G_TOTAL / 4) {
        ((int4*)first)[i] = inf4;
        ((int4*)rank)[i] = inf4;
    }
    if (i < W) bits[i] = 0ull;
    if (i < MAX_VOX / 4) {
        ((int4*)vcount)[i] = m14;
        ((int4*)cellOfRank)[i] = m14;
    }
    if (i < 2) dcount[i] = 0;
}

// K2: FUSED points + distinct-count + guard (3 dispatches -> 1).
// - Prefix-only claims (i < K), 4 pts/thread for MLP=4 (round-5/6 lessons).
// - Distinct count from atomicMin return (old==INF exactly once per cell),
//   LDS-reduced to ONE atomicAdd per block (round-5's regression was ~31K
//   wave-level adds to a single address; 256 block-level adds are free).
// - Last-block pattern: threadfence + done-counter; the final block re-reads
//   dcount and, ONLY if the prefix yielded < MAX_VOX distinct cells, repairs
//   by claiming points K..n itself (filtered atomicMin — exact under stale
//   reads since first[] only decreases). Rare path is slow (1 block) but
//   correct for any input; common path never takes it.
// Stream order guarantees kMark (next dispatch) sees the final first[].
__global__ __launch_bounds__(256) void kPointsCG(const float4* __restrict__ pts,
                                                 int* __restrict__ first,
                                                 int* __restrict__ dcount,
                                                 int K, int n) {
    __shared__ int wsh[4];
    __shared__ int repairFlag;
    int t = threadIdx.x;
    int i0 = blockIdx.x * 1024 + t;
    int i1 = i0 + 256, i2 = i0 + 512, i3 = i0 + 768;
    int m = K - 1;
    float4 p0 = pts[i0 < K ? i0 : m];
    float4 p1 = pts[i1 < K ? i1 : m];
    float4 p2 = pts[i2 < K ? i2 : m];
    float4 p3 = pts[i3 < K ? i3 : m];
    bool k0, k1, k2, k3;
    int c0 = cell_of(p0, k0);
    int c1 = cell_of(p1, k1);
    int c2 = cell_of(p2, k2);
    int c3 = cell_of(p3, k3);
    int have = 0;
    if (k0 && i0 < K) have += (atomicMin(&first[c0], i0) == INF_SENTINEL);
    if (k1 && i1 < K) have += (atomicMin(&first[c1], i1) == INF_SENTINEL);
    if (k2 && i2 < K) have += (atomicMin(&first[c2], i2) == INF_SENTINEL);
    if (k3 && i3 < K) have += (atomicMin(&first[c3], i3) == INF_SENTINEL);
    for (int d = 32; d >= 1; d >>= 1) have += __shfl_down(have, d, 64);
    if ((t & 63) == 0) wsh[t >> 6] = have;
    __syncthreads();
    if (t == 0) {
        repairFlag = 0;
        int part = wsh[0] + wsh[1] + wsh[2] + wsh[3];
        if (part) atomicAdd(&dcount[0], part);
        __threadfence();
        if (atomicAdd(&dcount[1], 1) == (int)gridDim.x - 1) {
            // all blocks' dcount contributions are visible (fence-before-done)
            int total = atomicAdd(&dcount[0], 0);
            repairFlag = (total < MAX_VOX);
        }
    }
    __syncthreads();
    if (repairFlag) {
        for (int i = K + t; i < n; i += 256) {
            float4 p = pts[i];
            bool ok;
            int c = cell_of(p, ok);
            if (ok && first[c] > i) atomicMin(&first[c], i);
        }
    }
}

// K3: set bit first[c] in the index-space bitmap. Distinct cells have
// distinct first indices; words shared by ~3 cells -> low-contention atomicOr.
__global__ __launch_bounds__(256) void kMark(const int* __restrict__ first,
                                             u64* __restrict__ bits) {
    int c = blockIdx.x * 256 + threadIdx.x;
    if (c >= G_TOTAL) return;
    int f = first[c];
    if (f != INF_SENTINEL) atomicOr(&bits[f >> 6], 1ull << (f & 63));
}

// K4: per-word intra-block exclusive prefix (wordLocal) + per-block sums.
__global__ __launch_bounds__(256) void kScan(const u64* __restrict__ bits,
                                             unsigned* __restrict__ wordLocal,
                                             int* __restrict__ sums, int W) {
    __shared__ int wsum[4], wexc[4];
    int t = threadIdx.x;
    int wi = blockIdx.x * 256 + t;
    u64 mask = (wi < W) ? bits[wi] : 0ull;
    int v = __popcll(mask);
    int lane = t & 63, w = t >> 6;
    int x = v;
    for (int d = 1; d < 64; d <<= 1) {
        int y = __shfl_up(x, d, 64);
        if (lane >= d) x += y;
    }
    if (lane == 63) wsum[w] = x;
    __syncthreads();
    if (t == 0) {
        int a = 0;
        for (int j = 0; j < 4; j++) { wexc[j] = a; a += wsum[j]; }
        sums[blockIdx.x] = a;
    }
    __syncthreads();
    if (wi < W) wordLocal[wi] = (unsigned)(wexc[w] + x - v);
}

// K5: materialize rank PER CELL (so the 2M-point append pass does only ONE
// random read). Each block redundantly exclusive-scans the (<=256) block
// sums in LDS. Also writes cellOfRank and num_voxels (block 0).
__global__ __launch_bounds__(256) void kRank(const int* __restrict__ first,
                                             const u64* __restrict__ bits,
                                             const unsigned* __restrict__ wordLocal,
                                             const int* __restrict__ sums,
                                             int nbW,
                                             int* __restrict__ rank,
                                             int* __restrict__ cellOfRank,
                                             float* __restrict__ nvOut) {
    __shared__ int sExc[256];
    __shared__ int wsum[4], wexc[4];
    int t = threadIdx.x;
    int v = (t < nbW) ? sums[t] : 0;
    int lane = t & 63, w = t >> 6;
    int x = v;
    for (int d = 1; d < 64; d <<= 1) {
        int y = __shfl_up(x, d, 64);
        if (lane >= d) x += y;
    }
    if (lane == 63) wsum[w] = x;
    __syncthreads();
    if (t == 0) {
        int a = 0;
        for (int j = 0; j < 4; j++) { wexc[j] = a; a += wsum[j]; }
        if (blockIdx.x == 0) nvOut[0] = (float)(a < MAX_VOX ? a : MAX_VOX);
    }
    __syncthreads();
    sExc[t] = wexc[w] + x - v;
    __syncthreads();

    int c = blockIdx.x * 256 + t;
    if (c >= G_TOTAL) return;
    int f = first[c];
    if (f == INF_SENTINEL) return;
    int wf = f >> 6, b = f & 63;
    u64 lowmask = (b == 0) ? 0ull : ((~0ull) >> (64 - b));
    int vr = sExc[wf >> 8] + (int)wordLocal[wf] + __popcll(bits[wf] & lowmask);
    rank[c] = vr;
    if (vr < MAX_VOX) cellOfRank[vr] = c;
}

// K6: append pass, 4 consecutive points/thread (64B contiguous per lane).
// Cells recomputed from pts (bitwise-identical IEEE ops; no lin[] array).
// rank loads issued UNCONDITIONALLY via clamped index (select after load,
// MLP=4 on the 2-level pts->rank chain). Unsigned compare so no rank value
// can index vcount negatively (round-4 lesson).
__global__ __launch_bounds__(256) void kAppend(const float4* __restrict__ pts,
                                               const int* __restrict__ rank,
                                               int* __restrict__ vcount,
                                               int* __restrict__ list, int n) {
    int gid = blockIdx.x * 256 + threadIdx.x;
    int nq = n >> 2;
    if (gid < nq) {
        int base = gid * 4;
        float4 p0 = pts[base + 0];
        float4 p1 = pts[base + 1];
        float4 p2 = pts[base + 2];
        float4 p3 = pts[base + 3];
        bool k0, k1, k2, k3;
        int c0 = cell_of(p0, k0);
        int c1 = cell_of(p1, k1);
        int c2 = cell_of(p2, k2);
        int c3 = cell_of(p3, k3);
        int r0 = rank[k0 ? c0 : 0];
        int r1 = rank[k1 ? c1 : 0];
        int r2 = rank[k2 ? c2 : 0];
        int r3 = rank[k3 ? c3 : 0];
        r0 = k0 ? r0 : INF_SENTINEL;
        r1 = k1 ? r1 : INF_SENTINEL;
        r2 = k2 ? r2 : INF_SENTINEL;
        r3 = k3 ? r3 : INF_SENTINEL;
#pragma unroll
        for (int j = 0; j < 4; j++) {
            int vr = j == 0 ? r0 : j == 1 ? r1 : j == 2 ? r2 : r3;
            if ((unsigned)vr >= MAX_VOX) continue;
            int pos = atomicAdd(&vcount[vr], 1) + 1;
            if (pos < CAP) list[vr * CAP + pos] = base + j;
        }
    }
    // scalar tail (n % 4), executed once
    if (gid == 0) {
        for (int i = nq << 2; i < n; i++) {
            float4 p = pts[i];
            bool ok;
            int c = cell_of(p, ok);
            if (!ok) continue;
            int vr = rank[c];
            if ((unsigned)vr >= MAX_VOX) continue;
            int pos = atomicAdd(&vcount[vr], 1) + 1;
            if (pos < CAP) list[vr * CAP + pos] = i;
        }
    }
}

// K7: 4 voxels per 256-thread block (one wave each). Counting-sort the
// collected indices (LDS broadcast reads), write all 32 slots + num_points
// + coors (so no d_out pre-memset is needed).
__global__ __launch_bounds__(256) void passF(const float4* __restrict__ pts,
                                             const int* __restrict__ vcount,
                                             const int* __restrict__ cellOfRank,
                                             const int* __restrict__ list,
                                             float4* __restrict__ voxOut,
                                             float* __restrict__ coorsOut,
                                             float* __restrict__ npOut) {
    __shared__ int s[4][CAP];
    __shared__ int slotPt[4][MAX_PTS];
    int w = threadIdx.x >> 6, lane = threadIdx.x & 63;
    int v = blockIdx.x * 4 + w;
    int cnt = vcount[v] + 1;
    int m = cnt < CAP ? cnt : CAP;
    s[w][lane] = (lane < m) ? list[v * CAP + lane] : 0x7FFFFFFF;
    if (lane < MAX_PTS) slotPt[w][lane] = -1;
    __syncthreads();
    int my = s[w][lane];
    int r = 0;
#pragma unroll
    for (int j = 0; j < CAP; j++) r += (s[w][j] < my) ? 1 : 0;  // broadcast
    if (lane < m && r < MAX_PTS) slotPt[w][r] = my;
    __syncthreads();
    if (lane < MAX_PTS) {
        int p = slotPt[w][lane];
        float4 val = make_float4(0.f, 0.f, 0.f, 0.f);
        if (p >= 0) val = pts[p];
        voxOut[(size_t)v * MAX_PTS + lane] = val;
    }
    if (lane == 0) {
        npOut[v] = (float)(cnt < MAX_PTS ? cnt : MAX_PTS);
        int cell = cellOfRank[v];
        if (cell < 0) {
            coorsOut[3 * v + 0] = -1.0f;
            coorsOut[3 * v + 1] = -1.0f;
            coorsOut[3 * v + 2] = -1.0f;
        } else {
            coorsOut[3 * v + 0] = 0.0f;  // cz (GZ==1)
            coorsOut[3 * v + 1] = (float)(cell / GX);
            coorsOut[3 * v + 2] = (float)(cell % GX);
        }
    }
}

extern "C" void kernel_launch(void* const* d_in, const int* in_sizes, int n_in,
                              void* d_out, int out_size, void* d_ws, size_t ws_size,
                              hipStream_t stream) {
    const float4* pts = (const float4*)d_in[0];
    int n = in_sizes[0] / 4;    // 2,000,000
    int W = (n + 63) >> 6;      // 31250 bitmap words
    int nbW = (W + 255) / 256;  // 123
    int K = PREFIX_K < n ? PREFIX_K : n;

    char* ws = (char*)d_ws;
    size_t off = 0;
    auto alloc = [&](size_t bytes) -> void* {
        void* p = (void*)(ws + off);
        off = (off + bytes + 255) & ~(size_t)255;
        return p;
    };
    int* first = (int*)alloc((size_t)G_TOTAL * 4);
    u64* bits = (u64*)alloc((size_t)W * 8);
    unsigned* wordLocal = (unsigned*)alloc((size_t)W * 4);
    int* sums = (int*)alloc(256 * 4);
    int* rank = (int*)alloc((size_t)G_TOTAL * 4);
    int* vcount = (int*)alloc((size_t)MAX_VOX * 4);
    int* cellOfRank = (int*)alloc((size_t)MAX_VOX * 4);
    int* dcount = (int*)alloc(256 * 4);
    int* list = (int*)alloc((size_t)MAX_VOX * CAP * 4);
    (void)ws_size;
    (void)n_in;
    (void)out_size;

    float* out = (float*)d_out;
    float4* voxOut = (float4*)out;                          // 20000*32*4
    float* coorsOut = out + (size_t)MAX_VOX * MAX_PTS * 4;  // 20000*3
    float* npOut = coorsOut + (size_t)MAX_VOX * 3;          // 20000
    float* nvOut = npOut + MAX_VOX;                         // 1

    // kInit grid must cover max(G_TOTAL/4, W, MAX_VOX/4) elements
    int mxI = G_TOTAL / 4;
    if (W > mxI) mxI = W;
    int nbI = (mxI + 255) / 256;           // 210
    int nbK = (K + 1023) / 1024;           // 256 (prefix, 4 pts/thread)
    int nbC = (G_TOTAL + 255) / 256;       // 837
    int nbA = ((n >> 2) + 255) / 256;      // 1954 (4 pts/thread)

    kInit<<<nbI, 256, 0, stream>>>(first, rank, bits, vcount, cellOfRank,
                                   dcount, W);
    kPointsCG<<<nbK, 256, 0, stream>>>(pts, first, dcount, K, n);
    kMark<<<nbC, 256, 0, stream>>>(first, bits);
    kScan<<<nbW, 256, 0, stream>>>(bits, wordLocal, sums, W);
    kRank<<<nbC, 256, 0, stream>>>(first, bits, wordLocal, sums, nbW, rank,
                                   cellOfRank, nvOut);
    kAppend<<<nbA, 256, 0, stream>>>(pts, rank, vcount, list, n);
    passF<<<MAX_VOX / 4, 256, 0, stream>>>(pts, vcount, cellOfRank, list,
                                           voxOut, coorsOut, npOut);
}